// Round 11
// baseline (318.315 us; speedup 1.0000x reference)
//
#include <hip/hip_runtime.h>
#include <hip/hip_cooperative_groups.h>
#include <hip/hip_bf16.h>
#include <stdint.h>
#include <string.h>

namespace cg = cooperative_groups;

typedef unsigned short u16;
typedef unsigned int u32;
typedef __bf16 bf16x8 __attribute__((ext_vector_type(8)));
typedef float f32x4 __attribute__((ext_vector_type(4)));
typedef unsigned int u32x2v __attribute__((ext_vector_type(2)));

// Problem constants
#define NB 4
#define NC 64
#define NH 8
#define NL 2048
#define HC 512   // H*C

// Workspace layout (bytes).
#define XT_OFF  ((size_t)0)          // bf16 xT[b][l][c]            1 MB
#define WM_OFF  ((size_t)1 << 20)    // bf16 Wm[tns][d][o][c]       576 KB
#define PBM_OFF ((size_t)2 << 20)    // f32  pbm[tns][o]            6 KB
#define V_OFF   ((size_t)4 << 20)    // bf16 v[b][o][l]             8 MB
#define QT_OFF  ((size_t)12 << 20)   // bf16 qT[bh][l][c]           8 MB
#define KT_OFF  ((size_t)20 << 20)   // bf16 kT[bh][l][c]           8 MB

#define LP 68   // padded LDS row stride (u16)
#define TILE_U16 (64 * LP)           // 4352 u16 = 8704 B

#if __has_builtin(__builtin_amdgcn_exp2f)
#define EXP2F __builtin_amdgcn_exp2f
#else
#define EXP2F exp2f
#endif

static __device__ __forceinline__ u16 f2bfu(float f) {
  union { float f; unsigned int i; } x; x.f = f;
  unsigned int i = x.i;
  return (u16)((i + 0x7fffu + ((i >> 16) & 1u)) >> 16);  // RTE, finite inputs
}
static __device__ __forceinline__ u32 pk2(float a, float b) {
  float2 f; f.x = a; f.y = b;
  __hip_bfloat162 h = __float22bfloat162_rn(f);
  u32 w; __builtin_memcpy(&w, &h, 4); return w;
}
static __device__ __forceinline__ bf16x8 ld_bf8(const u16* p) {
  bf16x8 v; __builtin_memcpy(&v, p, 16); return v;
}
static __device__ __forceinline__ bf16x8 frag_from4(u32 a, u32 b, u32 c, u32 d) {
  u32 t[4] = {a, b, c, d};
  bf16x8 v; __builtin_memcpy(&v, t, 16); return v;
}
static __device__ __forceinline__ void st_frag(u16* p, u32 a, u32 b, u32 c, u32 d) {
  u32 t[4] = {a, b, c, d};
  __builtin_memcpy(p, t, 16);
}

// Quad exchange (element-wise verified; used in 4 verified epilogues).
#define XCHG(X_, Y_, Fa_, Fb_)                                              \
  {                                                                         \
    u32x2v a_ = __builtin_amdgcn_permlane32_swap((X_), (Y_), false, false); \
    u32x2v b_ = __builtin_amdgcn_permlane16_swap(a_.x, a_.y, false, false); \
    Fa_ = b_.x; Fb_ = b_.y;                                                 \
  }

// ===========================================================================
// FUSED cooperative kernel: 512 blocks x 512 threads (2/CU x 256 CU
// co-resident). Phase 0 prep -> grid.sync -> phase 1 qkv -> grid.sync ->
// phase 2 attn. Deletes 2 kernel-launch gaps + dispatch-front drains, and
// makes total GPU time visible as ONE dispatch. LDS union 43.8 KB.
// ===========================================================================
__global__ __launch_bounds__(512, 4) void fused_all(
    const float* __restrict__ x,
    const float* __restrict__ qdw, const float* __restrict__ qdb,
    const float* __restrict__ qpw, const float* __restrict__ qpb,
    const float* __restrict__ kdw, const float* __restrict__ kdb,
    const float* __restrict__ kpw, const float* __restrict__ kpb,
    const float* __restrict__ vdw, const float* __restrict__ vdb,
    const float* __restrict__ vpw, const float* __restrict__ vpb,
    const float* __restrict__ ub,  const float* __restrict__ uw,
    u16* __restrict__ Wm, float* __restrict__ pbm, u16* __restrict__ xT,
    u16* __restrict__ v, u16* __restrict__ qT, u16* __restrict__ kT,
    float* __restrict__ outg)
{
  __shared__ __align__(16) char LB[43792];
  cg::grid_group grid = cg::this_grid();

  int bx = blockIdx.x;
  int tid = threadIdx.x;
  int wave = tid >> 6, lane = tid & 63, quad = lane >> 4, l16 = lane & 15;

  // ---------------- phase 0: prep (block-aligned idx ranges) --------------
  {
    int idx = bx * 512 + tid;
    if (idx < 65536) {
      // init_out: out[b,c,l] = ub[c]; 2 float4 per thread
#pragma unroll
      for (int jj = 0; jj < 2; ++jj) {
        int i4 = idx * 2 + jj;
        int c = (i4 >> 9) & 63;
        float f = ub[c];
        float4 vv = {f, f, f, f};
        ((float4*)outg)[i4] = vv;
      }
    } else if (idx < 165376) {
      int widx = idx - 65536;
      if (widx < 98304) {
        int tns = widx >> 15, r = widx & 32767, o = r >> 6, c = r & 63;
        const float* dw = (tns == 0) ? qdw : (tns == 1) ? kdw : vdw;
        const float* pw = (tns == 0) ? qpw : (tns == 1) ? kpw : vpw;
        float s = (tns == 0) ? 0.35355339059327373f * 1.4426950408889634f
                : (tns == 1) ? 0.35355339059327373f : 1.0f;
        float w = pw[o * 64 + c] * s;
#pragma unroll
        for (int d = 0; d < 3; ++d)
          Wm[((size_t)(tns * 3 + d) * 512 + o) * 64 + c] = f2bfu(w * dw[c * 3 + d]);
      } else {
        int i = widx - 98304;
        int tns = i >> 9, o = i & 511;
        const float* db = (tns == 0) ? qdb : (tns == 1) ? kdb : vdb;
        const float* pw = (tns == 0) ? qpw : (tns == 1) ? kpw : vpw;
        const float* pb = (tns == 0) ? qpb : (tns == 1) ? kpb : vpb;
        float s = (tns == 0) ? 0.35355339059327373f * 1.4426950408889634f
                : (tns == 1) ? 0.35355339059327373f : 1.0f;
        float bias = pb[o];
        for (int c = 0; c < 64; ++c) bias += pw[o * 64 + c] * db[c];
        pbm[i] = bias * s;
      }
    } else if (idx < 198144) {
      // prep_x: x[b][c][l] f32 -> xT[b][l][c] bf16, via LDS transpose.
      // Two 256-thread sub-instances per block (blocks 323..386).
      int t = idx - 165376;
      int j = t >> 8, tid8 = t & 255, sub = tid >> 8;
      u16* T = (u16*)LB + sub * TILE_U16;
      int lt = j & 31, bb = j >> 5;
      {
        int c = tid8 & 63, ls = (tid8 >> 6) * 16;
        const float4* g = (const float4*)(x + ((size_t)bb * NC + c) * NL + lt * 64 + ls);
        u16 tmp[16];
#pragma unroll
        for (int j4 = 0; j4 < 4; ++j4) {
          float4 f = g[j4];
          tmp[j4*4+0] = f2bfu(f.x); tmp[j4*4+1] = f2bfu(f.y);
          tmp[j4*4+2] = f2bfu(f.z); tmp[j4*4+3] = f2bfu(f.w);
        }
#pragma unroll
        for (int jj = 0; jj < 16; ++jj) T[(ls + jj) * LP + c] = tmp[jj];
      }
      __syncthreads();
      {
        int r = tid8 >> 2, cs = (tid8 & 3) * 16;
        uint4 a = *(const uint4*)&T[r * LP + cs];
        uint4 b3 = *(const uint4*)&T[r * LP + cs + 8];
        u16* o = xT + ((size_t)bb * NL + lt * 64 + r) * 64 + cs;
        *(uint4*)o = a;
        *(uint4*)(o + 8) = b3;
      }
    }
  }
  grid.sync();

  // ---------------- phase 1: qkv (3 units of 64o x 128l per block) --------
  {
    u16* WS = (u16*)LB;                       // [d][o][c], d stride TILE_U16
    u16* XS = (u16*)(LB + 26112);             // [130][LP]
    uint4 Z = {0, 0, 0, 0};

    for (int u = 0; u < 3; ++u) {
      int g = bx + u * 512;
      int lg = g & 15, och = (g >> 4) & 7, tmp2 = g >> 7;
      int tns = tmp2 % 3, b = tmp2 / 3;
      int L0 = lg * 128;
      const u16* xg = xT + (size_t)b * NL * 64;

      // stage weights (1536 uint4, 3/thread)
      {
        const u16* wg = Wm + ((size_t)(tns * 3) * 512 + och * 64) * 64;
#pragma unroll
        for (int it = 0; it < 3; ++it) {
          int s = tid + it * 512;
          int d = s >> 9, r = s & 511, o = r >> 3, c4 = r & 7;
          uint4 w = *(const uint4*)(wg + ((size_t)d * 512 + o) * 64 + c4 * 8);
          *(uint4*)&WS[(size_t)d * TILE_U16 + o * LP + c4 * 8] = w;
        }
      }
      // stage X rows L0-1 .. L0+128 (130 rows, zero-padded)
      {
        int xr = tid >> 3, xc = (tid & 7) * 8;
#pragma unroll
        for (int jj = 0; jj < 2; ++jj) {
          int r = xr + 64 * jj;
          int gl = L0 - 1 + r;
          uint4 w = ((unsigned)gl < NL) ? *(const uint4*)(xg + (size_t)gl * 64 + xc) : Z;
          *(uint4*)&XS[r * LP + xc] = w;
        }
        if (tid < 16) {
          int r = 128 + (tid >> 3);
          int gl = L0 - 1 + r;
          uint4 w = ((unsigned)gl < NL) ? *(const uint4*)(xg + (size_t)gl * 64 + xc) : Z;
          *(uint4*)&XS[r * LP + xc] = w;
        }
      }
      __syncthreads();

      if (tns != 2) {
        // q/k: wave -> 64o x 16l at l = L0 + wave*16 + l16 (r10 epilogue)
        f32x4 acc[4] = {{0,0,0,0},{0,0,0,0},{0,0,0,0},{0,0,0,0}};
#pragma unroll
        for (int d = 0; d < 3; ++d)
#pragma unroll
          for (int kh = 0; kh < 2; ++kh) {
            bf16x8 xf = ld_bf8(&XS[(wave * 16 + l16 + d) * LP + kh * 32 + quad * 8]);
#pragma unroll
            for (int nt = 0; nt < 4; ++nt) {
              bf16x8 wf = ld_bf8(&WS[(size_t)d * TILE_U16 + (nt * 16 + l16) * LP + kh * 32 + quad * 8]);
              acc[nt] = __builtin_amdgcn_mfma_f32_16x16x32_bf16(wf, xf, acc[nt], 0, 0, 0);
            }
          }
        float4 bq4[4];
        const float* pbt = pbm + tns * 512 + och * 64;
#pragma unroll
        for (int nt = 0; nt < 4; ++nt)
          bq4[nt] = *(const float4*)(pbt + nt * 16 + quad * 4);
        u32 w01[4], w23[4];
#pragma unroll
        for (int nt = 0; nt < 4; ++nt) {
          w01[nt] = pk2(acc[nt][0] + bq4[nt].x, acc[nt][1] + bq4[nt].y);
          w23[nt] = pk2(acc[nt][2] + bq4[nt].z, acc[nt][3] + bq4[nt].w);
        }
        int l = L0 + wave * 16 + l16;
        u16* dst = (tns == 0) ? qT : kT;
        u16* qp = dst + ((size_t)(b * 8 + och) * NL + l) * 64;
#pragma unroll
        for (int kh = 0; kh < 2; ++kh) {
          u32 F0, F1, F2, F3;
          XCHG(w01[2 * kh], w01[2 * kh + 1], F0, F2);
          XCHG(w23[2 * kh], w23[2 * kh + 1], F1, F3);
          st_frag(qp + kh * 32 + quad * 8, F0, F1, F2, F3);
        }
      } else {
        // v: wave -> 16o x 64l; ot4 = wave&3 (o block), lh = wave>>2 (l half)
        int ot4 = wave & 3, lh = wave >> 2;
        f32x4 acc[4] = {{0,0,0,0},{0,0,0,0},{0,0,0,0},{0,0,0,0}};
#pragma unroll
        for (int d = 0; d < 3; ++d)
#pragma unroll
          for (int kh = 0; kh < 2; ++kh) {
            bf16x8 wf = ld_bf8(&WS[(size_t)d * TILE_U16 + (ot4 * 16 + l16) * LP + kh * 32 + quad * 8]);
#pragma unroll
            for (int lt = 0; lt < 4; ++lt) {
              bf16x8 xf = ld_bf8(&XS[(lh * 64 + lt * 16 + l16 + d) * LP + kh * 32 + quad * 8]);
              acc[lt] = __builtin_amdgcn_mfma_f32_16x16x32_bf16(xf, wf, acc[lt], 0, 0, 0);
            }
          }
        float bvv = pbm[2 * 512 + och * 64 + ot4 * 16 + l16];
        u32 a01[4], a23[4];
#pragma unroll
        for (int lt = 0; lt < 4; ++lt) {
          a01[lt] = pk2(acc[lt][0] + bvv, acc[lt][1] + bvv);
          a23[lt] = pk2(acc[lt][2] + bvv, acc[lt][3] + bvv);
        }
        u16* vp = v + ((size_t)(b * HC + och * 64 + ot4 * 16 + l16)) * NL + L0 + lh * 64;
        {
          u32 F0, F1, F2, F3;
          XCHG(a01[0], a01[1], F0, F2);
          XCHG(a23[0], a23[1], F1, F3);
          st_frag(vp + quad * 8, F0, F1, F2, F3);
        }
        {
          u32 F0, F1, F2, F3;
          XCHG(a01[2], a01[3], F0, F2);
          XCHG(a23[2], a23[3], F1, F3);
          st_frag(vp + 32 + quad * 8, F0, F1, F2, F3);
        }
      }
      if (u < 2) __syncthreads();   // LDS reuse across units
    }
  }
  grid.sync();

  // ---------------- phase 2: attn + fused unify (r8 verbatim) -------------
  {
    u16* KT0 = (u16*)LB;                    // Kt[2][64][LP]
    u16* VT0 = (u16*)(LB + 17408);          // Vt[2][64][LP]
    u16* UW  = (u16*)(LB + 34816);          // UW[64][LP]

    int qt = bx & 15, bh = bx >> 4;
    int b = bh >> 3, h = bh & 7;

    const u16* Qh = qT + (size_t)bh * NL * 64;
    const u16* Kh = kT + (size_t)bh * NL * 64;
    const u16* Vh = v + ((size_t)(b * HC + h * NC)) * NL;
    int q0 = qt * 128;

    int sr = tid >> 3, ss = (tid & 7) * 8;
    int vc = tid >> 3, vk = (tid & 7) * 8;

    // stage UW head slice as bf16
    {
      int c = tid >> 3, gg = (tid & 7) * 8;
      const float4* s = (const float4*)(uw + (size_t)c * HC + h * 64 + gg);
      float4 w0 = s[0], w1 = s[1];
      u16* d = &UW[c * LP + gg];
      d[0] = f2bfu(w0.x); d[1] = f2bfu(w0.y); d[2] = f2bfu(w0.z); d[3] = f2bfu(w0.w);
      d[4] = f2bfu(w1.x); d[5] = f2bfu(w1.y); d[6] = f2bfu(w1.z); d[7] = f2bfu(w1.w);
    }

    // K/V tile loads + buf0 fill, tile1 prefetch
    uint4 ka, va;
    {
      ka = *(const uint4*)(Kh + (size_t)sr * 64 + ss);
      va = *(const uint4*)(Vh + (size_t)vc * NL + vk);
      *(uint4*)&KT0[sr * LP + ss] = ka;
      *(uint4*)&VT0[vc * LP + vk] = va;
      ka = *(const uint4*)(Kh + (size_t)(64 + sr) * 64 + ss);
      va = *(const uint4*)(Vh + (size_t)vc * NL + 64 + vk);
    }

    bf16x8 bq[2];
#pragma unroll
    for (int kh = 0; kh < 2; ++kh)
      bq[kh] = ld_bf8(Qh + (size_t)(q0 + wave * 16 + l16) * 64 + kh * 32 + quad * 8);

    bf16x8 ones = frag_from4(0x3F803F80u, 0x3F803F80u, 0x3F803F80u, 0x3F803F80u);

    __syncthreads();

    f32x4 o[4];
#pragma unroll
    for (int ct = 0; ct < 4; ++ct) o[ct] = (f32x4){0, 0, 0, 0};
    f32x4 lacc = {0, 0, 0, 0};

    for (int i = 0; i < 32; ++i) {
      int cur = i & 1;
      u16* Ktc = KT0 + cur * TILE_U16;
      u16* Vtc = VT0 + cur * TILE_U16;
      bf16x8 ak[4][2], av[4][2];
#pragma unroll
      for (int j = 0; j < 4; ++j)
#pragma unroll
        for (int kh = 0; kh < 2; ++kh) {
          ak[j][kh] = ld_bf8(&Ktc[(j * 16 + l16) * LP + kh * 32 + quad * 8]);
          av[j][kh] = ld_bf8(&Vtc[(j * 16 + l16) * LP + kh * 32 + quad * 8]);
        }

      f32x4 s[4];
#pragma unroll
      for (int ktl = 0; ktl < 4; ++ktl) {
        f32x4 z = {0, 0, 0, 0};
        z = __builtin_amdgcn_mfma_f32_16x16x32_bf16(ak[ktl][0], bq[0], z, 0, 0, 0);
        z = __builtin_amdgcn_mfma_f32_16x16x32_bf16(ak[ktl][1], bq[1], z, 0, 0, 0);
        s[ktl] = z;
      }
      u32 w01[4], w23[4];
#pragma unroll
      for (int ktl = 0; ktl < 4; ++ktl) {
        float p0 = EXP2F(s[ktl][0]);
        float p1 = EXP2F(s[ktl][1]);
        float p2 = EXP2F(s[ktl][2]);
        float p3 = EXP2F(s[ktl][3]);
        w01[ktl] = pk2(p0, p1);
        w23[ktl] = pk2(p2, p3);
      }
#pragma unroll
      for (int kh = 0; kh < 2; ++kh) {
        u32 F0, F1, F2, F3;
        XCHG(w01[2 * kh], w01[2 * kh + 1], F0, F2);
        XCHG(w23[2 * kh], w23[2 * kh + 1], F1, F3);
        bf16x8 bp = frag_from4(F0, F1, F2, F3);
        lacc = __builtin_amdgcn_mfma_f32_16x16x32_bf16(ones, bp, lacc, 0, 0, 0);
#pragma unroll
        for (int ct = 0; ct < 4; ++ct)
          o[ct] = __builtin_amdgcn_mfma_f32_16x16x32_bf16(av[ct][kh], bp, o[ct], 0, 0, 0);
      }

      if (i < 31) {
        int nxt = cur ^ 1;
        *(uint4*)&KT0[nxt * TILE_U16 + sr * LP + ss] = ka;
        *(uint4*)&VT0[nxt * TILE_U16 + vc * LP + vk] = va;
        if (i < 30) {
          int kt2 = (i + 2) * 64;
          ka = *(const uint4*)(Kh + (size_t)(kt2 + sr) * 64 + ss);
          va = *(const uint4*)(Vh + (size_t)vc * NL + kt2 + vk);
        }
      }
      __syncthreads();
    }

    // epilogue
    float* ob = outg + ((size_t)b * NC) * NL;
    {
      float rinv = 1.0f / lacc[0];
      u32 w01[4], w23[4];
#pragma unroll
      for (int ct = 0; ct < 4; ++ct) {
        w01[ct] = pk2(o[ct][0] * rinv, o[ct][1] * rinv);
        w23[ct] = pk2(o[ct][2] * rinv, o[ct][3] * rinv);
      }
      bf16x8 ot[2];
#pragma unroll
      for (int kh = 0; kh < 2; ++kh) {
        u32 F0, F1, F2, F3;
        XCHG(w01[2 * kh], w01[2 * kh + 1], F0, F2);
        XCHG(w23[2 * kh], w23[2 * kh + 1], F1, F3);
        ot[kh] = frag_from4(F0, F1, F2, F3);
      }
      int qcol = q0 + wave * 16 + l16;
#pragma unroll
      for (int mt = 0; mt < 4; ++mt) {
        f32x4 acc = {0, 0, 0, 0};
#pragma unroll
        for (int kh = 0; kh < 2; ++kh) {
          bf16x8 a = ld_bf8(&UW[(mt * 16 + l16) * LP + kh * 32 + quad * 8]);
          acc = __builtin_amdgcn_mfma_f32_16x16x32_bf16(a, ot[kh], acc, 0, 0, 0);
        }
#pragma unroll
        for (int rr = 0; rr < 4; ++rr) {
          int c = mt * 16 + quad * 4 + rr;
          atomicAdd(&ob[(size_t)c * NL + qcol], acc[rr]);
        }
      }
    }
  }
}

// ===========================================================================
// Fallback 3-kernel path (r10/r8, proven @152.8-153.3 us) in case the
// cooperative launch is rejected under graph capture.
// ===========================================================================
__global__ __launch_bounds__(256) void prep_all(
    const float* __restrict__ x,
    const float* __restrict__ qdw, const float* __restrict__ qdb,
    const float* __restrict__ qpw, const float* __restrict__ qpb,
    const float* __restrict__ kdw, const float* __restrict__ kdb,
    const float* __restrict__ kpw, const float* __restrict__ kpb,
    const float* __restrict__ vdw, const float* __restrict__ vdb,
    const float* __restrict__ vpw, const float* __restrict__ vpb,
    const float* __restrict__ ub,
    u16* __restrict__ Wm, float* __restrict__ pbm,
    u16* __restrict__ xT, float* __restrict__ out)
{
  __shared__ __align__(16) u16 T[64 * LP];
  int bx = blockIdx.x;
  int tid = threadIdx.x;

  if (bx < 512) {
    int i4 = bx * 256 + tid;
    int c = (i4 >> 9) & 63;
    float f = ub[c];
    float4 v = {f, f, f, f};
    ((float4*)out)[i4] = v;
    return;
  }
  if (bx < 902) {
    int idx = (bx - 512) * 256 + tid;
    if (idx < 98304) {
      int tns = idx >> 15, r = idx & 32767, o = r >> 6, c = r & 63;
      const float* dw = (tns == 0) ? qdw : (tns == 1) ? kdw : vdw;
      const float* pw = (tns == 0) ? qpw : (tns == 1) ? kpw : vpw;
      float s = (tns == 0) ? 0.35355339059327373f * 1.4426950408889634f
              : (tns == 1) ? 0.35355339059327373f : 1.0f;
      float w = pw[o * 64 + c] * s;
#pragma unroll
      for (int d = 0; d < 3; ++d)
        Wm[((size_t)(tns * 3 + d) * 512 + o) * 64 + c] = f2bfu(w * dw[c * 3 + d]);
    } else {
      int i = idx - 98304;
      int tns = i >> 9, o = i & 511;
      const float* db = (tns == 0) ? qdb : (tns == 1) ? kdb : vdb;
      const float* pw = (tns == 0) ? qpw : (tns == 1) ? kpw : vpw;
      const float* pb = (tns == 0) ? qpb : (tns == 1) ? kpb : vpb;
      float s = (tns == 0) ? 0.35355339059327373f * 1.4426950408889634f
              : (tns == 1) ? 0.35355339059327373f : 1.0f;
      float bias = pb[o];
      for (int c = 0; c < 64; ++c) bias += pw[o * 64 + c] * db[c];
      pbm[i] = bias * s;
    }
    return;
  }
  {
    int b2 = bx - 902;
    int lt = b2 & 31, b = b2 >> 5;
    {
      int c = tid & 63, ls = (tid >> 6) * 16;
      const float4* g = (const float4*)(x + ((size_t)b * NC + c) * NL + lt * 64 + ls);
      u16 tmp[16];
#pragma unroll
      for (int j4 = 0; j4 < 4; ++j4) {
        float4 f = g[j4];
        tmp[j4*4+0] = f2bfu(f.x); tmp[j4*4+1] = f2bfu(f.y);
        tmp[j4*4+2] = f2bfu(f.z); tmp[j4*4+3] = f2bfu(f.w);
      }
#pragma unroll
      for (int j = 0; j < 16; ++j) T[(ls + j) * LP + c] = tmp[j];
    }
    __syncthreads();
    {
      int r = tid >> 2, cs = (tid & 3) * 16;
      uint4 a = *(const uint4*)&T[r * LP + cs];
      uint4 b3 = *(const uint4*)&T[r * LP + cs + 8];
      u16* o = xT + ((size_t)b * NL + lt * 64 + r) * 64 + cs;
      *(uint4*)o = a;
      *(uint4*)(o + 8) = b3;
    }
  }
}

__global__ __launch_bounds__(256) void qkv_gemm(
    const u16* __restrict__ xT, const u16* __restrict__ Wm,
    const float* __restrict__ pbm,
    u16* __restrict__ v, u16* __restrict__ qT, u16* __restrict__ kT)
{
  __shared__ __align__(16) u16 WS[3][64 * LP];
  __shared__ __align__(16) u16 XS[130 * LP];

  int bx = blockIdx.x;
  int lg  = bx & 15;
  int och = (bx >> 4) & 7;
  int tmp = bx >> 7;
  int tns = tmp % 3;
  int b   = tmp / 3;

  int tid = threadIdx.x;
  int wave = tid >> 6, lane = tid & 63, quad = lane >> 4, l16 = lane & 15;
  const u16* xg = xT + (size_t)b * NL * 64;
  int L0 = lg * 128;
  uint4 Z = {0, 0, 0, 0};

  {
    const u16* wg = Wm + ((size_t)(tns * 3) * 512 + och * 64) * 64;
#pragma unroll
    for (int it = 0; it < 6; ++it) {
      int s = tid + it * 256;
      int d = s >> 9, r = s & 511;
      int o = r >> 3, c4 = r & 7;
      uint4 w = *(const uint4*)(wg + ((size_t)d * 512 + o) * 64 + c4 * 8);
      *(uint4*)&WS[d][o * LP + c4 * 8] = w;
    }
  }
  {
    int xr = tid >> 3, xc = (tid & 7) * 8;
#pragma unroll
    for (int j = 0; j < 4; ++j) {
      int r = xr + 32 * j;
      int g = L0 - 1 + r;
      uint4 w = ((unsigned)g < NL) ? *(const uint4*)(xg + (size_t)g * 64 + xc) : Z;
      *(uint4*)&XS[r * LP + xc] = w;
    }
    if (tid < 16) {
      int r = 128 + (tid >> 3);
      int g = L0 - 1 + r;
      uint4 w = ((unsigned)g < NL) ? *(const uint4*)(xg + (size_t)g * 64 + xc) : Z;
      *(uint4*)&XS[r * LP + xc] = w;
    }
  }
  __syncthreads();

  f32x4 acc[8] = {{0,0,0,0},{0,0,0,0},{0,0,0,0},{0,0,0,0},
                  {0,0,0,0},{0,0,0,0},{0,0,0,0},{0,0,0,0}};

  if (tns != 2) {
    float4 bq4[4];
    const float* pbt = pbm + tns * 512 + och * 64;
#pragma unroll
    for (int nt = 0; nt < 4; ++nt)
      bq4[nt] = *(const float4*)(pbt + nt * 16 + quad * 4);

#pragma unroll
    for (int d = 0; d < 3; ++d)
#pragma unroll
      for (int kh = 0; kh < 2; ++kh) {
        bf16x8 wf[4], xf[2];
#pragma unroll
        for (int nt = 0; nt < 4; ++nt)
          wf[nt] = ld_bf8(&WS[d][(nt * 16 + l16) * LP + kh * 32 + quad * 8]);
#pragma unroll
        for (int lt = 0; lt < 2; ++lt)
          xf[lt] = ld_bf8(&XS[(wave * 32 + lt * 16 + l16 + d) * LP + kh * 32 + quad * 8]);
#pragma unroll
        for (int nt = 0; nt < 4; ++nt)
#pragma unroll
          for (int lt = 0; lt < 2; ++lt)
            acc[nt * 2 + lt] = __builtin_amdgcn_mfma_f32_16x16x32_bf16(
                wf[nt], xf[lt], acc[nt * 2 + lt], 0, 0, 0);
      }

    u16* dst = (tns == 0) ? qT : kT;
#pragma unroll
    for (int lt = 0; lt < 2; ++lt) {
      u32 w01[4], w23[4];
#pragma unroll
      for (int nt = 0; nt < 4; ++nt) {
        w01[nt] = pk2(acc[nt * 2 + lt][0] + bq4[nt].x, acc[nt * 2 + lt][1] + bq4[nt].y);
        w23[nt] = pk2(acc[nt * 2 + lt][2] + bq4[nt].z, acc[nt * 2 + lt][3] + bq4[nt].w);
      }
      int l = L0 + wave * 32 + lt * 16 + l16;
      u16* qp = dst + ((size_t)(b * 8 + och) * NL + l) * 64;
#pragma unroll
      for (int kh = 0; kh < 2; ++kh) {
        u32 F0, F1, F2, F3;
        XCHG(w01[2 * kh], w01[2 * kh + 1], F0, F2);
        XCHG(w23[2 * kh], w23[2 * kh + 1], F1, F3);
        st_frag(qp + kh * 32 + quad * 8, F0, F1, F2, F3);
      }
    }
  } else {
    float bv4[4];
#pragma unroll
    for (int ot = 0; ot < 4; ++ot)
      bv4[ot] = pbm[tns * 512 + och * 64 + ot * 16 + l16];

#pragma unroll
    for (int d = 0; d < 3; ++d)
#pragma unroll
      for (int kh = 0; kh < 2; ++kh) {
        bf16x8 wf[4], xf[2];
#pragma unroll
        for (int ot = 0; ot < 4; ++ot)
          wf[ot] = ld_bf8(&WS[d][(ot * 16 + l16) * LP + kh * 32 + quad * 8]);
#pragma unroll
        for (int lt = 0; lt < 2; ++lt)
          xf[lt] = ld_bf8(&XS[(wave * 32 + lt * 16 + l16 + d) * LP + kh * 32 + quad * 8]);
#pragma unroll
        for (int lt = 0; lt < 2; ++lt)
#pragma unroll
          for (int ot = 0; ot < 4; ++ot)
            acc[lt * 4 + ot] = __builtin_amdgcn_mfma_f32_16x16x32_bf16(
                xf[lt], wf[ot], acc[lt * 4 + ot], 0, 0, 0);
      }

#pragma unroll
    for (int ot = 0; ot < 4; ++ot) {
      u32 a01[2], a23[2];
#pragma unroll
      for (int lt = 0; lt < 2; ++lt) {
        a01[lt] = pk2(acc[lt * 4 + ot][0] + bv4[ot], acc[lt * 4 + ot][1] + bv4[ot]);
        a23[lt] = pk2(acc[lt * 4 + ot][2] + bv4[ot], acc[lt * 4 + ot][3] + bv4[ot]);
      }
      u16* vp = v + ((size_t)(b * HC + och * 64 + ot * 16 + l16)) * NL + L0 + wave * 32;
      u32 F0, F1, F2, F3;
      XCHG(a01[0], a01[1], F0, F2);
      XCHG(a23[0], a23[1], F1, F3);
      st_frag(vp + quad * 8, F0, F1, F2, F3);
    }
  }
}

__global__ __launch_bounds__(512, 4) void attn_kernel(
    const u16* __restrict__ qT, const u16* __restrict__ kT,
    const u16* __restrict__ vg, const float* __restrict__ uw,
    float* __restrict__ outg)
{
  __shared__ __align__(16) u16 Kt[2][64 * LP];
  __shared__ __align__(16) u16 Vt[2][64 * LP];
  __shared__ __align__(16) u16 UW[64 * LP];

  int bx = blockIdx.x;
  int qt = bx & 15, bh = bx >> 4;
  int b = bh >> 3, h = bh & 7;
  int tid = threadIdx.x;
  int wave = tid >> 6, lane = tid & 63, quad = lane >> 4, l16 = lane & 15;

  const u16* Qh = qT + (size_t)bh * NL * 64;
  const u16* Kh = kT + (size_t)bh * NL * 64;
  const u16* Vh = vg + ((size_t)(b * HC + h * NC)) * NL;
  int q0 = qt * 128;

  int sr = tid >> 3, ss = (tid & 7) * 8;
  int vc = tid >> 3, vk = (tid & 7) * 8;

  {
    int c = tid >> 3, g = (tid & 7) * 8;
    const float4* s = (const float4*)(uw + (size_t)c * HC + h * 64 + g);
    float4 w0 = s[0], w1 = s[1];
    u16* d = &UW[c * LP + g];
    d[0] = f2bfu(w0.x); d[1] = f2bfu(w0.y); d[2] = f2bfu(w0.z); d[3] = f2bfu(w0.w);
    d[4] = f2bfu(w1.x); d[5] = f2bfu(w1.y); d[6] = f2bfu(w1.z); d[7] = f2bfu(w1.w);
  }

  uint4 ka, va;
  {
    ka = *(const uint4*)(Kh + (size_t)sr * 64 + ss);
    va = *(const uint4*)(Vh + (size_t)vc * NL + vk);
    *(uint4*)&Kt[0][sr * LP + ss] = ka;
    *(uint4*)&Vt[0][vc * LP + vk] = va;
    ka = *(const uint4*)(Kh + (size_t)(64 + sr) * 64 + ss);
    va = *(const uint4*)(Vh + (size_t)vc * NL + 64 + vk);
  }

  bf16x8 bq[2];
#pragma unroll
  for (int kh = 0; kh < 2; ++kh)
    bq[kh] = ld_bf8(Qh + (size_t)(q0 + wave * 16 + l16) * 64 + kh * 32 + quad * 8);

  bf16x8 ones = frag_from4(0x3F803F80u, 0x3F803F80u, 0x3F803F80u, 0x3F803F80u);

  __syncthreads();

  f32x4 o[4];
#pragma unroll
  for (int ct = 0; ct < 4; ++ct) o[ct] = (f32x4){0, 0, 0, 0};
  f32x4 lacc = {0, 0, 0, 0};

  for (int i = 0; i < 32; ++i) {
    int cur = i & 1;
    bf16x8 ak[4][2], av[4][2];
#pragma unroll
    for (int j = 0; j < 4; ++j)
#pragma unroll
      for (int kh = 0; kh < 2; ++kh) {
        ak[j][kh] = ld_bf8(&Kt[cur][(j * 16 + l16) * LP + kh * 32 + quad * 8]);
        av[j][kh] = ld_bf8(&Vt[cur][(j * 16 + l16) * LP + kh * 32 + quad * 8]);
      }

    f32x4 s[4];
#pragma unroll
    for (int ktl = 0; ktl < 4; ++ktl) {
      f32x4 z = {0, 0, 0, 0};
      z = __builtin_amdgcn_mfma_f32_16x16x32_bf16(ak[ktl][0], bq[0], z, 0, 0, 0);
      z = __builtin_amdgcn_mfma_f32_16x16x32_bf16(ak[ktl][1], bq[1], z, 0, 0, 0);
      s[ktl] = z;
    }
    u32 w01[4], w23[4];
#pragma unroll
    for (int ktl = 0; ktl < 4; ++ktl) {
      float p0 = EXP2F(s[ktl][0]);
      float p1 = EXP2F(s[ktl][1]);
      float p2 = EXP2F(s[ktl][2]);
      float p3 = EXP2F(s[ktl][3]);
      w01[ktl] = pk2(p0, p1);
      w23[ktl] = pk2(p2, p3);
    }
#pragma unroll
    for (int kh = 0; kh < 2; ++kh) {
      u32 F0, F1, F2, F3;
      XCHG(w01[2 * kh], w01[2 * kh + 1], F0, F2);
      XCHG(w23[2 * kh], w23[2 * kh + 1], F1, F3);
      bf16x8 bp = frag_from4(F0, F1, F2, F3);
      lacc = __builtin_amdgcn_mfma_f32_16x16x32_bf16(ones, bp, lacc, 0, 0, 0);
#pragma unroll
      for (int ct = 0; ct < 4; ++ct)
        o[ct] = __builtin_amdgcn_mfma_f32_16x16x32_bf16(av[ct][kh], bp, o[ct], 0, 0, 0);
    }

    if (i < 31) {
      int nxt = cur ^ 1;
      *(uint4*)&Kt[nxt][sr * LP + ss] = ka;
      *(uint4*)&Vt[nxt][vc * LP + vk] = va;
      if (i < 30) {
        int kt2 = (i + 2) * 64;
        ka = *(const uint4*)(Kh + (size_t)(kt2 + sr) * 64 + ss);
        va = *(const uint4*)(Vh + (size_t)vc * NL + kt2 + vk);
      }
    }
    __syncthreads();
  }

  float* ob = outg + ((size_t)b * NC) * NL;
  {
    float rinv = 1.0f / lacc[0];
    u32 w01[4], w23[4];
#pragma unroll
    for (int ct = 0; ct < 4; ++ct) {
      w01[ct] = pk2(o[ct][0] * rinv, o[ct][1] * rinv);
      w23[ct] = pk2(o[ct][2] * rinv, o[ct][3] * rinv);
    }
    bf16x8 ot[2];
#pragma unroll
    for (int kh = 0; kh < 2; ++kh) {
      u32 F0, F1, F2, F3;
      XCHG(w01[2 * kh], w01[2 * kh + 1], F0, F2);
      XCHG(w23[2 * kh], w23[2 * kh + 1], F1, F3);
      ot[kh] = frag_from4(F0, F1, F2, F3);
    }
    int qcol = q0 + wave * 16 + l16;
#pragma unroll
    for (int mt = 0; mt < 4; ++mt) {
      f32x4 acc = {0, 0, 0, 0};
#pragma unroll
      for (int kh = 0; kh < 2; ++kh) {
        bf16x8 a = ld_bf8(&UW[(mt * 16 + l16) * LP + kh * 32 + quad * 8]);
        acc = __builtin_amdgcn_mfma_f32_16x16x32_bf16(a, ot[kh], acc, 0, 0, 0);
      }
#pragma unroll
      for (int rr = 0; rr < 4; ++rr) {
        int c = mt * 16 + quad * 4 + rr;
        atomicAdd(&ob[(size_t)c * NL + qcol], acc[rr]);
      }
    }
  }
}

// ---------------------------------------------------------------------------
extern "C" void kernel_launch(void* const* d_in, const int* in_sizes, int n_in,
                              void* d_out, int out_size, void* d_ws, size_t ws_size,
                              hipStream_t stream) {
  (void)in_sizes; (void)n_in; (void)out_size; (void)ws_size;
  const float* x   = (const float*)d_in[0];
  const float* qdw = (const float*)d_in[1];
  const float* qdb = (const float*)d_in[2];
  const float* qpw = (const float*)d_in[3];
  const float* qpb = (const float*)d_in[4];
  const float* kdw = (const float*)d_in[5];
  const float* kdb = (const float*)d_in[6];
  const float* kpw = (const float*)d_in[7];
  const float* kpb = (const float*)d_in[8];
  const float* vdw = (const float*)d_in[9];
  const float* vdb = (const float*)d_in[10];
  const float* vpw = (const float*)d_in[11];
  const float* vpb = (const float*)d_in[12];
  const float* uw  = (const float*)d_in[13];
  const float* ub  = (const float*)d_in[14];

  char* ws = (char*)d_ws;
  u16*   xT  = (u16*)(ws + XT_OFF);
  u16*   Wm  = (u16*)(ws + WM_OFF);
  float* pbm = (float*)(ws + PBM_OFF);
  u16*   v   = (u16*)(ws + V_OFF);
  u16*   qT  = (u16*)(ws + QT_OFF);
  u16*   kT  = (u16*)(ws + KT_OFF);
  float* out = (float*)d_out;

  void* args[] = {
      (void*)&x,  (void*)&qdw, (void*)&qdb, (void*)&qpw, (void*)&qpb,
      (void*)&kdw, (void*)&kdb, (void*)&kpw, (void*)&kpb,
      (void*)&vdw, (void*)&vdb, (void*)&vpw, (void*)&vpb,
      (void*)&ub, (void*)&uw,
      (void*)&Wm, (void*)&pbm, (void*)&xT,
      (void*)&v, (void*)&qT, (void*)&kT, (void*)&out};

  hipError_t err = hipLaunchCooperativeKernel(
      (void*)fused_all, dim3(512), dim3(512), args, 0, stream);

  if (err != hipSuccess) {
    // Fallback: proven 3-kernel path (r10/r8).
    prep_all<<<1030, 256, 0, stream>>>(
        x, qdw, qdb, qpw, qpb, kdw, kdb, kpw, kpb, vdw, vdb, vpw, vpb,
        ub, Wm, pbm, xT, out);
    qkv_gemm<<<1536, 256, 0, stream>>>(xT, Wm, pbm, v, qT, kT);
    attn_kernel<<<512, 512, 0, stream>>>(qT, kT, v, uw, out);
  }
}

// Round 12
// 150.647 us; speedup vs baseline: 2.1130x; 2.1130x over previous
//
#include <hip/hip_runtime.h>
#include <hip/hip_bf16.h>
#include <stdint.h>
#include <string.h>

typedef unsigned short u16;
typedef unsigned int u32;
typedef __bf16 bf16x8 __attribute__((ext_vector_type(8)));
typedef float f32x4 __attribute__((ext_vector_type(4)));
typedef unsigned int u32x2v __attribute__((ext_vector_type(2)));

// Problem constants
#define NB 4
#define NC 64
#define NH 8
#define NL 2048
#define HC 512   // H*C

// Workspace layout (bytes).
#define XT_OFF  ((size_t)0)          // bf16 xT[b][l][c]            1 MB
#define WM_OFF  ((size_t)1 << 20)    // bf16 Wm[tns][d][o][c]       576 KB
#define PBM_OFF ((size_t)2 << 20)    // f32  pbm[tns][o]            6 KB
#define V_OFF   ((size_t)4 << 20)    // bf16 v[b][o][l]             8 MB
#define QT_OFF  ((size_t)12 << 20)   // bf16 qT[bh][l][c]           8 MB
#define KT_OFF  ((size_t)20 << 20)   // bf16 kT[bh][l][c]           8 MB

#define LP 68   // padded LDS row stride (u16); 136B = 34 words -> 2-bank row
                // rotation: 16-row fragment reads are 2-way (free per m136)

#if __has_builtin(__builtin_amdgcn_exp2f)
#define EXP2F __builtin_amdgcn_exp2f
#else
#define EXP2F exp2f
#endif

static __device__ __forceinline__ u16 f2bfu(float f) {
  union { float f; unsigned int i; } x; x.f = f;
  unsigned int i = x.i;
  return (u16)((i + 0x7fffu + ((i >> 16) & 1u)) >> 16);  // RTE, finite inputs
}
static __device__ __forceinline__ u32 pk2(float a, float b) {
  float2 f; f.x = a; f.y = b;
  __hip_bfloat162 h = __float22bfloat162_rn(f);   // packed cvt on gfx950
  u32 w; __builtin_memcpy(&w, &h, 4); return w;
}
static __device__ __forceinline__ bf16x8 ld_bf8(const u16* p) {
  bf16x8 v; __builtin_memcpy(&v, p, 16); return v;
}
static __device__ __forceinline__ bf16x8 frag_from4(u32 a, u32 b, u32 c, u32 d) {
  u32 t[4] = {a, b, c, d};
  bf16x8 v; __builtin_memcpy(&v, t, 16); return v;
}
static __device__ __forceinline__ void st_frag(u16* p, u32 a, u32 b, u32 c, u32 d) {
  u32 t[4] = {a, b, c, d};
  __builtin_memcpy(p, t, 16);
}

// Quad exchange: pairs C-layout tiles along the ROW-block axis into
// per-lane contiguous row-runs at fixed col (element-wise verified vs the
// attn PV mapping; used in 4 verified epilogues). Fa = rows +0..3 halves,
// Fb = rows +4..7 halves.
#define XCHG(X_, Y_, Fa_, Fb_)                                              \
  {                                                                         \
    u32x2v a_ = __builtin_amdgcn_permlane32_swap((X_), (Y_), false, false); \
    u32x2v b_ = __builtin_amdgcn_permlane16_swap(a_.x, a_.y, false, false); \
    Fa_ = b_.x; Fb_ = b_.y;                                                 \
  }

// ---------------------------------------------------------------------------
// Kernel P: fused prep. Block ranges:
//  [0,512)    init_out: out[b,c,l] = ub[c]
//  [512,902)  prep_w: merged conv weights + folded bias
//  [902,1030) prep_x: x[b][c][l] f32 -> xT[b][l][c] bf16
// ---------------------------------------------------------------------------
__global__ __launch_bounds__(256) void prep_all(
    const float* __restrict__ x,
    const float* __restrict__ qdw, const float* __restrict__ qdb,
    const float* __restrict__ qpw, const float* __restrict__ qpb,
    const float* __restrict__ kdw, const float* __restrict__ kdb,
    const float* __restrict__ kpw, const float* __restrict__ kpb,
    const float* __restrict__ vdw, const float* __restrict__ vdb,
    const float* __restrict__ vpw, const float* __restrict__ vpb,
    const float* __restrict__ ub,
    u16* __restrict__ Wm, float* __restrict__ pbm,
    u16* __restrict__ xT, float* __restrict__ out)
{
  __shared__ __align__(16) u16 T[64 * LP];
  int bx = blockIdx.x;
  int tid = threadIdx.x;

  if (bx < 512) {
    int i4 = bx * 256 + tid;     // float4 index
    int c = (i4 >> 9) & 63;
    float f = ub[c];
    float4 v = {f, f, f, f};
    ((float4*)out)[i4] = v;
    return;
  }
  if (bx < 902) {
    int idx = (bx - 512) * 256 + tid;
    if (idx < 98304) {
      int tns = idx >> 15, r = idx & 32767, o = r >> 6, c = r & 63;
      const float* dw = (tns == 0) ? qdw : (tns == 1) ? kdw : vdw;
      const float* pw = (tns == 0) ? qpw : (tns == 1) ? kpw : vpw;
      float s = (tns == 0) ? 0.35355339059327373f * 1.4426950408889634f
              : (tns == 1) ? 0.35355339059327373f : 1.0f;
      float w = pw[o * 64 + c] * s;
#pragma unroll
      for (int d = 0; d < 3; ++d)
        Wm[((size_t)(tns * 3 + d) * 512 + o) * 64 + c] = f2bfu(w * dw[c * 3 + d]);
    } else {
      int i = idx - 98304;
      int tns = i >> 9, o = i & 511;
      const float* db = (tns == 0) ? qdb : (tns == 1) ? kdb : vdb;
      const float* pw = (tns == 0) ? qpw : (tns == 1) ? kpw : vpw;
      const float* pb = (tns == 0) ? qpb : (tns == 1) ? kpb : vpb;
      float s = (tns == 0) ? 0.35355339059327373f * 1.4426950408889634f
              : (tns == 1) ? 0.35355339059327373f : 1.0f;
      float bias = pb[o];
      for (int c = 0; c < 64; ++c) bias += pw[o * 64 + c] * db[c];
      pbm[i] = bias * s;
    }
    return;
  }
  // prep_x
  {
    int b2 = bx - 902;
    int lt = b2 & 31, b = b2 >> 5;
    {
      int c = tid & 63, ls = (tid >> 6) * 16;
      const float4* g = (const float4*)(x + ((size_t)b * NC + c) * NL + lt * 64 + ls);
      u16 tmp[16];
#pragma unroll
      for (int j4 = 0; j4 < 4; ++j4) {
        float4 f = g[j4];
        tmp[j4*4+0] = f2bfu(f.x); tmp[j4*4+1] = f2bfu(f.y);
        tmp[j4*4+2] = f2bfu(f.z); tmp[j4*4+3] = f2bfu(f.w);
      }
#pragma unroll
      for (int j = 0; j < 16; ++j) T[(ls + j) * LP + c] = tmp[j];
    }
    __syncthreads();
    {
      int r = tid >> 2, cs = (tid & 3) * 16;
      uint4 a = *(const uint4*)&T[r * LP + cs];
      uint4 b3 = *(const uint4*)&T[r * LP + cs + 8];
      u16* o = xT + ((size_t)b * NL + lt * 64 + r) * 64 + cs;
      *(uint4*)o = a;
      *(uint4*)(o + 8) = b3;
    }
  }
}

// ---------------------------------------------------------------------------
// Kernel 1: qkv via MFMA (r8 -- measured best, total 152.8 us). 4 l-tiles
// per block, XS double-buffered with register prefetch, ONE barrier per
// tile. Operand-swapped MFMAs put the output's contiguous dim on the C
// rows; epilogue transposes in registers (XCHG) and stores straight to
// global (no OS staging). LDS 43.1 KB -> 3/CU.
//   q/k: acc[nt] = mfma(W(nt), X)  -> rows=o, cols=l -> XCHG -> qT[l][c]
//   v:   acc[nt] = mfma(X(nt), W)  -> rows=l, cols=o -> XCHG -> v[o][l]
// ---------------------------------------------------------------------------
__global__ __launch_bounds__(256) void qkv_gemm(
    const u16* __restrict__ xT, const u16* __restrict__ Wm,
    const float* __restrict__ pbm,
    u16* __restrict__ v, u16* __restrict__ qT, u16* __restrict__ kT)
{
  __shared__ __align__(16) u16 WS[3][64 * LP];   // WS[d][o][c]
  __shared__ __align__(16) u16 XS[2][66 * LP];   // XS[buf][r][c], r0 = l0-1

  int bx = blockIdx.x;
  int lg  = bx & 7;
  int och = (bx >> 3) & 7;
  int tmp = bx >> 6;
  int tns = tmp % 3;
  int b   = tmp / 3;

  int tid = threadIdx.x;
  int wave = tid >> 6, lane = tid & 63, quad = lane >> 4, l16 = lane & 15;
  const u16* xg = xT + (size_t)b * NL * 64;

  // stage merged weights once (o-chunk slice, 3 d-slices)
  {
    const u16* wg = Wm + ((size_t)(tns * 3) * 512 + och * 64) * 64;
#pragma unroll
    for (int it = 0; it < 6; ++it) {
      int s = tid + it * 256;
      int d = s >> 9, r = s & 511;
      int o = r >> 3, c4 = r & 7;
      uint4 w = *(const uint4*)(wg + ((size_t)d * 512 + o) * 64 + c4 * 8);
      *(uint4*)&WS[d][o * LP + c4 * 8] = w;
    }
  }

  // XS prefetch helpers: 528 uint4 slots (66 rows x 8), <=3 per thread
  int xr0 = tid >> 3,          xc0 = (tid & 7) * 8;
  int xr1 = (tid + 256) >> 3,  xc1 = xc0;
  int xr2 = (tid + 512) >> 3,  xc2 = xc0;
  uint4 R0, R1, R2;
  uint4 Z = {0, 0, 0, 0};

#define LOAD_XS(tt)                                                         \
  {                                                                         \
    int base = (lg * 4 + (tt)) * 64 - 1;                                    \
    int g0 = base + xr0, g1 = base + xr1, g2 = base + xr2;                  \
    R0 = ((unsigned)g0 < NL) ? *(const uint4*)(xg + (size_t)g0 * 64 + xc0) : Z; \
    R1 = ((unsigned)g1 < NL) ? *(const uint4*)(xg + (size_t)g1 * 64 + xc1) : Z; \
    if (tid < 16)                                                           \
      R2 = ((unsigned)g2 < NL) ? *(const uint4*)(xg + (size_t)g2 * 64 + xc2) : Z; \
  }
#define STORE_XS(bf)                                                        \
  {                                                                         \
    *(uint4*)&XS[bf][xr0 * LP + xc0] = R0;                                  \
    *(uint4*)&XS[bf][xr1 * LP + xc1] = R1;                                  \
    if (tid < 16) *(uint4*)&XS[bf][xr2 * LP + xc2] = R2;                    \
  }

  LOAD_XS(0); STORE_XS(0);
  LOAD_XS(1);
  __syncthreads();

  // bias regs + v-path hoisted W fragments (tile-invariant, 6 regs)
  float4 bq4[4];          // tns!=2: bias by o = nt*16 + quad*4 + rr
  float bvv = 0.f;        // tns==2: bias by o = wave*16 + l16 (lane-uniform)
  bf16x8 aw[3][2];
  if (tns == 2) {
    bvv = pbm[tns * 512 + och * 64 + wave * 16 + l16];
#pragma unroll
    for (int d = 0; d < 3; ++d)
#pragma unroll
      for (int kh = 0; kh < 2; ++kh)
        aw[d][kh] = ld_bf8(&WS[d][(wave * 16 + l16) * LP + kh * 32 + quad * 8]);
  } else {
    const float* pbt = pbm + tns * 512 + och * 64;
#pragma unroll
    for (int nt = 0; nt < 4; ++nt)
      bq4[nt] = *(const float4*)(pbt + nt * 16 + quad * 4);
  }

  for (int t = 0; t < 4; ++t) {
    int cur = t & 1;
    f32x4 acc[4] = {{0,0,0,0},{0,0,0,0},{0,0,0,0},{0,0,0,0}};

    if (tns == 2) {
      // v: A = X (rows=l blocks nt), B = W (cols = o, this wave's 16)
#pragma unroll
      for (int nt = 0; nt < 4; ++nt)
#pragma unroll
        for (int d = 0; d < 3; ++d)
#pragma unroll
          for (int kh = 0; kh < 2; ++kh) {
            bf16x8 bx8 = ld_bf8(&XS[cur][(nt * 16 + l16 + d) * LP + kh * 32 + quad * 8]);
            acc[nt] = __builtin_amdgcn_mfma_f32_16x16x32_bf16(bx8, aw[d][kh], acc[nt], 0, 0, 0);
          }
    } else {
      // q/k: A = W (rows=o blocks nt), B = X (cols = l, this wave's 16)
      bf16x8 ax[3][2];
#pragma unroll
      for (int d = 0; d < 3; ++d)
#pragma unroll
        for (int kh = 0; kh < 2; ++kh)
          ax[d][kh] = ld_bf8(&XS[cur][(wave * 16 + l16 + d) * LP + kh * 32 + quad * 8]);
#pragma unroll
      for (int nt = 0; nt < 4; ++nt)
#pragma unroll
        for (int d = 0; d < 3; ++d)
#pragma unroll
          for (int kh = 0; kh < 2; ++kh) {
            bf16x8 bw = ld_bf8(&WS[d][(nt * 16 + l16) * LP + kh * 32 + quad * 8]);
            acc[nt] = __builtin_amdgcn_mfma_f32_16x16x32_bf16(bw, ax[d][kh], acc[nt], 0, 0, 0);
          }
    }

    if (t < 3) { STORE_XS((t + 1) & 1); if (t < 2) LOAD_XS(t + 2); }
    __syncthreads();   // XS[next] ready; epilogue below is LDS-free

    // in-register transpose epilogue + direct coalesced global stores
    int lt = lg * 4 + t;
    if (tns == 2) {
      // acc rows = l (nt blocks), col o = wave*16+l16; bias lane-uniform
      u32 w01[4], w23[4];
#pragma unroll
      for (int nt = 0; nt < 4; ++nt) {
        w01[nt] = pk2(acc[nt][0] + bvv, acc[nt][1] + bvv);
        w23[nt] = pk2(acc[nt][2] + bvv, acc[nt][3] + bvv);
      }
      u16* vp = v + ((size_t)(b * HC + och * 64 + wave * 16 + l16)) * NL + lt * 64;
#pragma unroll
      for (int kh = 0; kh < 2; ++kh) {
        u32 F0, F1, F2, F3;
        XCHG(w01[2 * kh], w01[2 * kh + 1], F0, F2);
        XCHG(w23[2 * kh], w23[2 * kh + 1], F1, F3);
        st_frag(vp + kh * 32 + quad * 8, F0, F1, F2, F3);  // 8 contiguous l
      }
    } else {
      // acc rows = o (nt blocks), col l = wave*16+l16; bias by (nt,rr)
      u32 w01[4], w23[4];
#pragma unroll
      for (int nt = 0; nt < 4; ++nt) {
        w01[nt] = pk2(acc[nt][0] + bq4[nt].x, acc[nt][1] + bq4[nt].y);
        w23[nt] = pk2(acc[nt][2] + bq4[nt].z, acc[nt][3] + bq4[nt].w);
      }
      u16* dst = (tns == 0) ? qT : kT;
      u16* qp = dst + ((size_t)(b * 8 + och) * NL + lt * 64 + wave * 16 + l16) * 64;
#pragma unroll
      for (int kh = 0; kh < 2; ++kh) {
        u32 F0, F1, F2, F3;
        XCHG(w01[2 * kh], w01[2 * kh + 1], F0, F2);
        XCHG(w23[2 * kh], w23[2 * kh + 1], F1, F3);
        st_frag(qp + kh * 32 + quad * 8, F0, F1, F2, F3);  // 8 contiguous c
      }
    }
  }
#undef LOAD_XS
#undef STORE_XS
}

// ---------------------------------------------------------------------------
// Kernel 2: flash attention + fused unify (r8 verbatim -- measured best,
// 62.0 us). 512 blocks = 32 bh * 16 q-tiles of 128. 8 waves * 16 queries.
// K/V LDS double-buffered, ONE barrier per key-tile iteration. In-register
// P/OT transposes (permlane). l-sum via ones-fragment MFMA. LDS 43.5 KB.
// ---------------------------------------------------------------------------
__global__ __launch_bounds__(512, 4) void attn_kernel(
    const u16* __restrict__ qT, const u16* __restrict__ kT,
    const u16* __restrict__ vg, const float* __restrict__ uw,
    float* __restrict__ outg)
{
  __shared__ __align__(16) u16 Kt[2][64 * LP];  // Kt[buf][key][c]
  __shared__ __align__(16) u16 Vt[2][64 * LP];  // Vt[buf][c][key]
  __shared__ __align__(16) u16 UW[64 * LP];     // UW[c][c']

  int bx = blockIdx.x;
  int qt = bx & 15, bh = bx >> 4;
  int b = bh >> 3, h = bh & 7;
  int tid = threadIdx.x;
  int wave = tid >> 6, lane = tid & 63, quad = lane >> 4, l16 = lane & 15;

  const u16* Qh = qT + (size_t)bh * NL * 64;
  const u16* Kh = kT + (size_t)bh * NL * 64;
  const u16* Vh = vg + ((size_t)(b * HC + h * NC)) * NL;
  int q0 = qt * 128;

  int sr = tid >> 3, ss = (tid & 7) * 8;    // K staging: row, u16-col (1 uint4/thread)
  int vc = tid >> 3, vk = (tid & 7) * 8;    // V staging: c row, key seg

  // stage UW head slice as bf16: UW[c][c'] = uw[c*512 + h*64 + c']
  {
    int c = tid >> 3, g = (tid & 7) * 8;
    const float4* s = (const float4*)(uw + (size_t)c * HC + h * 64 + g);
    float4 w0 = s[0], w1 = s[1];
    u16* d = &UW[c * LP + g];
    d[0] = f2bfu(w0.x); d[1] = f2bfu(w0.y); d[2] = f2bfu(w0.z); d[3] = f2bfu(w0.w);
    d[4] = f2bfu(w1.x); d[5] = f2bfu(w1.y); d[6] = f2bfu(w1.z); d[7] = f2bfu(w1.w);
  }

  // K/V tile loads (regs) + buf0 fill, tile1 prefetch (1 uint4 each/thread)
  uint4 ka, va;
  {
    ka = *(const uint4*)(Kh + (size_t)sr * 64 + ss);
    va = *(const uint4*)(Vh + (size_t)vc * NL + vk);
    *(uint4*)&Kt[0][sr * LP + ss] = ka;
    *(uint4*)&Vt[0][vc * LP + vk] = va;
    ka = *(const uint4*)(Kh + (size_t)(64 + sr) * 64 + ss);
    va = *(const uint4*)(Vh + (size_t)vc * NL + 64 + vk);
  }

  // Q fragments for this wave's 16 queries, straight from global (no LDS)
  bf16x8 bq[2];
#pragma unroll
  for (int kh = 0; kh < 2; ++kh)
    bq[kh] = ld_bf8(Qh + (size_t)(q0 + wave * 16 + l16) * 64 + kh * 32 + quad * 8);

  // all-ones A fragment for MFMA l-sum (column sums of P)
  bf16x8 ones = frag_from4(0x3F803F80u, 0x3F803F80u, 0x3F803F80u, 0x3F803F80u);

  __syncthreads();

  f32x4 o[4];
#pragma unroll
  for (int ct = 0; ct < 4; ++ct) o[ct] = (f32x4){0, 0, 0, 0};
  f32x4 lacc = {0, 0, 0, 0};

  for (int i = 0; i < 32; ++i) {
    int cur = i & 1;
    // K and V fragments (full 64-key tile per wave)
    bf16x8 ak[4][2], av[4][2];
#pragma unroll
    for (int j = 0; j < 4; ++j)
#pragma unroll
      for (int kh = 0; kh < 2; ++kh) {
        ak[j][kh] = ld_bf8(&Kt[cur][(j * 16 + l16) * LP + kh * 32 + quad * 8]);
        av[j][kh] = ld_bf8(&Vt[cur][(j * 16 + l16) * LP + kh * 32 + quad * 8]);
      }

    // S = K^T Q (rows=keys, cols=queries), log2 domain
    f32x4 s[4];
#pragma unroll
    for (int ktl = 0; ktl < 4; ++ktl) {
      f32x4 z = {0, 0, 0, 0};
      z = __builtin_amdgcn_mfma_f32_16x16x32_bf16(ak[ktl][0], bq[0], z, 0, 0, 0);
      z = __builtin_amdgcn_mfma_f32_16x16x32_bf16(ak[ktl][1], bq[1], z, 0, 0, 0);
      s[ktl] = z;
    }
    // p = 2^s; pack to bf16 pairs per ktl: w01=keys(+0,+1), w23=keys(+2,+3)
    u32 w01[4], w23[4];
#pragma unroll
    for (int ktl = 0; ktl < 4; ++ktl) {
      float p0 = EXP2F(s[ktl][0]);
      float p1 = EXP2F(s[ktl][1]);
      float p2 = EXP2F(s[ktl][2]);
      float p3 = EXP2F(s[ktl][3]);
      w01[ktl] = pk2(p0, p1);
      w23[ktl] = pk2(p2, p3);
    }
    // in-register transpose to PV B-fragments; O += V*P; l += colsum(P)
#pragma unroll
    for (int kh = 0; kh < 2; ++kh) {
      u32 F0, F1, F2, F3;
      XCHG(w01[2 * kh], w01[2 * kh + 1], F0, F2);
      XCHG(w23[2 * kh], w23[2 * kh + 1], F1, F3);
      bf16x8 bp = frag_from4(F0, F1, F2, F3);
      lacc = __builtin_amdgcn_mfma_f32_16x16x32_bf16(ones, bp, lacc, 0, 0, 0);
#pragma unroll
      for (int ct = 0; ct < 4; ++ct)
        o[ct] = __builtin_amdgcn_mfma_f32_16x16x32_bf16(av[ct][kh], bp, o[ct], 0, 0, 0);
    }

    if (i < 31) {
      int nxt = cur ^ 1;
      *(uint4*)&Kt[nxt][sr * LP + ss] = ka;
      *(uint4*)&Vt[nxt][vc * LP + vk] = va;
      if (i < 30) {
        int kt2 = (i + 2) * 64;
        ka = *(const uint4*)(Kh + (size_t)(kt2 + sr) * 64 + ss);
        va = *(const uint4*)(Vh + (size_t)vc * NL + kt2 + vk);
      }
    }
    __syncthreads();   // the ONLY barrier per iteration
  }

  // epilogue: lacc[0] = l for query l16 (ones-MFMA, rows all equal)
  float* ob = outg + ((size_t)b * NC) * NL;
  {
    float rinv = 1.0f / lacc[0];

    // pack normalized O (rows=c', cols=q) then quad-exchange to B-fragments
    u32 w01[4], w23[4];
#pragma unroll
    for (int ct = 0; ct < 4; ++ct) {
      w01[ct] = pk2(o[ct][0] * rinv, o[ct][1] * rinv);
      w23[ct] = pk2(o[ct][2] * rinv, o[ct][3] * rinv);
    }
    bf16x8 ot[2];
#pragma unroll
    for (int kh = 0; kh < 2; ++kh) {
      u32 F0, F1, F2, F3;
      XCHG(w01[2 * kh], w01[2 * kh + 1], F0, F2);
      XCHG(w23[2 * kh], w23[2 * kh + 1], F1, F3);
      ot[kh] = frag_from4(F0, F1, F2, F3);
    }

    int qcol = q0 + wave * 16 + l16;
#pragma unroll
    for (int mt = 0; mt < 4; ++mt) {
      f32x4 acc = {0, 0, 0, 0};
#pragma unroll
      for (int kh = 0; kh < 2; ++kh) {
        bf16x8 a = ld_bf8(&UW[(mt * 16 + l16) * LP + kh * 32 + quad * 8]);
        acc = __builtin_amdgcn_mfma_f32_16x16x32_bf16(a, ot[kh], acc, 0, 0, 0);
      }
#pragma unroll
      for (int rr = 0; rr < 4; ++rr) {
        int c = mt * 16 + quad * 4 + rr;
        atomicAdd(&ob[(size_t)c * NL + qcol], acc[rr]);
      }
    }
  }
}

// ---------------------------------------------------------------------------
extern "C" void kernel_launch(void* const* d_in, const int* in_sizes, int n_in,
                              void* d_out, int out_size, void* d_ws, size_t ws_size,
                              hipStream_t stream) {
  (void)in_sizes; (void)n_in; (void)out_size; (void)ws_size;
  const float* x   = (const float*)d_in[0];
  const float* qdw = (const float*)d_in[1];
  const float* qdb = (const float*)d_in[2];
  const float* qpw = (const float*)d_in[3];
  const float* qpb = (const float*)d_in[4];
  const float* kdw = (const float*)d_in[5];
  const float* kdb = (const float*)d_in[6];
  const float* kpw = (const float*)d_in[7];
  const float* kpb = (const float*)d_in[8];
  const float* vdw = (const float*)d_in[9];
  const float* vdb = (const float*)d_in[10];
  const float* vpw = (const float*)d_in[11];
  const float* vpb = (const float*)d_in[12];
  const float* uw  = (const float*)d_in[13];
  const float* ub  = (const float*)d_in[14];

  char* ws = (char*)d_ws;
  u16*   xT  = (u16*)(ws + XT_OFF);
  u16*   Wm  = (u16*)(ws + WM_OFF);
  float* pbm = (float*)(ws + PBM_OFF);
  u16*   v   = (u16*)(ws + V_OFF);
  u16*   qT  = (u16*)(ws + QT_OFF);
  u16*   kT  = (u16*)(ws + KT_OFF);
  float* out = (float*)d_out;

  prep_all<<<1030, 256, 0, stream>>>(
      x, qdw, qdb, qpw, qpb, kdw, kdb, kpw, kpb, vdw, vdb, vpw, vpb,
      ub, Wm, pbm, xT, out);
  qkv_gemm<<<768, 256, 0, stream>>>(xT, Wm, pbm, v, qT, kT);
  attn_kernel<<<512, 512, 0, stream>>>(qT, kT, v, uw, out);
}